// Round 1
// baseline (705.733 us; speedup 1.0000x reference)
//
#include <hip/hip_runtime.h>

typedef short short8 __attribute__((ext_vector_type(8)));
typedef float f32x4 __attribute__((ext_vector_type(4)));
typedef unsigned int uint;

#define C_IN  128
#define H_IN  112
#define W_IN  112
#define K_OUT 256
#define H_OUTD 110
#define W_OUTD 110
#define NBATCH 32

// xT layout: [n][ph(2)][h(112)][w(112)][64] bf16, swizzled within 64: pos = (c&63) ^ ((w&7)<<3)
#define XT_ELEMS (NBATCH*2*H_IN*W_IN*64)   // 51,380,224
#define F_ELEMS  (9*K_OUT*C_IN)            // 294,912

__device__ __forceinline__ unsigned short f2bf(float f) {
  uint u = __float_as_uint(f);
  u += 0x7fffu + ((u >> 16) & 1u);   // RNE (inputs are finite, no NaN handling needed)
  return (unsigned short)(u >> 16);
}

// ---------------- prep: x (NCHW f32) -> xT (swizzled bf16) ----------------
__global__ __launch_bounds__(256) void xpose_kernel(const float* __restrict__ x,
                                                    unsigned short* __restrict__ xT) {
  __shared__ unsigned short sm[H_IN * 128];   // [w][c''] 28,672 B
  const int n = blockIdx.y;
  const int h = blockIdx.x;
  const int tid = threadIdx.x;
  // phase 1: coalesced read along w; swizzled LDS write (c-pair packed b32)
  for (int it = 0; it < 28; ++it) {
    int idx = it*256 + tid;            // 0..7167  (64 c-pairs x 112 w)
    int w  = idx % 112;
    int cp = idx / 112;                // 0..63
    int c0 = cp*2;
    const float* px = x + ((size_t)(n*C_IN + c0)*H_IN + h)*W_IN + w;
    float f0 = px[0];
    float f1 = px[H_IN*W_IN];
    uint key  = ((uint)w & 7u) << 3;
    uint cpos = ((uint)c0 & 64u) | (((uint)c0 & 63u) ^ key);
    uint v = (uint)f2bf(f0) | ((uint)f2bf(f1) << 16);
    *(uint*)&sm[w*128 + cpos] = v;
  }
  __syncthreads();
  // phase 2: linear LDS->global copy (fully coalesced dwordx4)
  for (int it = 0; it < 7; ++it) {
    int idx = it*256 + tid;            // 0..1791
    int ph  = idx / 896;
    int rem = idx - ph*896;
    int w   = rem >> 3;
    int ck  = rem & 7;
    uint4 v = *(const uint4*)&sm[w*128 + ph*64 + ck*8];
    int off = (((n*2 + ph)*H_IN + h)*W_IN + w)*64 + ck*8;
    *(uint4*)&xT[off] = v;
  }
}

// ---------------- prep: filt (OIHW f32) -> F[rs][k][c] bf16 ----------------
__global__ __launch_bounds__(256) void fprep_kernel(const float* __restrict__ ft,
                                                    unsigned short* __restrict__ F) {
  int idx = blockIdx.x*256 + threadIdx.x;   // < 294912
  int rs  = idx >> 15;                      // /32768  (256*128)
  int rem = idx & 32767;
  int k   = rem >> 7;
  int c   = rem & 127;
  F[idx] = f2bf(ft[(k*C_IN + c)*9 + rs]);
}

// ---------------- main implicit-GEMM conv ----------------
// block: 512 thr (8 waves, 4M x 2N), tile = 256 K_out x 128 pixels, K=1152
__global__ __launch_bounds__(512, 2) void conv_gemm(const unsigned short* __restrict__ xT,
                                                    const unsigned short* __restrict__ F,
                                                    float* __restrict__ out) {
  __shared__ unsigned short sm[450*64];     // rows (rr*112+w'), 57,600 B
  const int tile = blockIdx.x;              // 0..96
  const int n    = blockIdx.y;
  const int tid  = threadIdx.x;
  const int lane = tid & 63;
  const int wid  = tid >> 6;
  const int wm   = wid & 3;                 // M quadrant (64 k each)
  const int wn   = wid >> 2;                // N half (64 pixels each)
  const int l15  = lane & 15;
  const int lhi  = lane >> 4;               // 0..3
  const int t0   = tile*128;
  const int h0   = t0 / 112;

  // per-n-tile pixel coords
  int rowb[4], wv[4], hv[4];
  #pragma unroll
  for (int nt = 0; nt < 4; ++nt) {
    int p = t0 + wn*64 + nt*16 + l15;
    int h = p / 112;
    int w = p - h*112;
    hv[nt] = h; wv[nt] = w;
    rowb[nt] = (h - h0)*112 + w;
  }
  int arow[4];
  #pragma unroll
  for (int mt = 0; mt < 4; ++mt) {
    int k = wm*64 + mt*16 + l15;
    arow[mt] = k*128;
  }

  f32x4 acc[4][4];
  #pragma unroll
  for (int mt = 0; mt < 4; ++mt)
    #pragma unroll
    for (int nt = 0; nt < 4; ++nt)
      acc[mt][nt] = (f32x4){0.f, 0.f, 0.f, 0.f};

  for (int ph = 0; ph < 2; ++ph) {
    if (ph) __syncthreads();
    // stage c-half ph: rows h0..h0+3 (clamped), linear LDS, conflict-free
    {
      const unsigned short* base = xT + (size_t)((n*2 + ph)*H_IN) * (W_IN*64);
      #pragma unroll
      for (int it = 0; it < 7; ++it) {
        int idx = it*512 + tid;        // < 3584
        int rr  = idx / 896;
        int rem = idx - rr*896;
        int hc  = h0 + rr; if (hc > 111) hc = 111;
        uint4 v = *((const uint4*)(base + hc*(W_IN*64)) + rem);
        *((uint4*)sm + idx) = v;
      }
    }
    __syncthreads();

    for (int rs = 0; rs < 9; ++rs) {
      int r = rs / 3;
      int s = rs - r*3;
      const unsigned short* Frs = F + rs*(K_OUT*C_IN) + ph*64;
      #pragma unroll
      for (int ch = 0; ch < 2; ++ch) {
        const int cb = ch*32 + lhi*8;             // c_local base (mult of 8)
        short8 a[4];
        #pragma unroll
        for (int mt = 0; mt < 4; ++mt)
          a[mt] = *(const short8*)(Frs + arow[mt] + cb);
        short8 b[4];
        #pragma unroll
        for (int nt = 0; nt < 4; ++nt) {
          int row  = rowb[nt] + r*112 + s;
          uint key = (((uint)(wv[nt] + s)) & 7u) << 3;
          uint cs  = (uint)cb ^ key;
          b[nt] = *(const short8*)&sm[row*64 + cs];
        }
        #pragma unroll
        for (int mt = 0; mt < 4; ++mt)
          #pragma unroll
          for (int nt = 0; nt < 4; ++nt)
            acc[mt][nt] = __builtin_amdgcn_mfma_f32_16x16x32_bf16(a[mt], b[nt], acc[mt][nt], 0, 0, 0);
      }
    }
  }

  // epilogue: D frag: col(N=pixel)=lane&15, row(M=k)=lhi*4+reg
  #pragma unroll
  for (int nt = 0; nt < 4; ++nt) {
    if (hv[nt] < H_OUTD && wv[nt] < W_OUTD) {
      float* po = out + (size_t)n*K_OUT*(H_OUTD*W_OUTD) + hv[nt]*W_OUTD + wv[nt];
      #pragma unroll
      for (int mt = 0; mt < 4; ++mt) {
        #pragma unroll
        for (int reg = 0; reg < 4; ++reg) {
          int k = wm*64 + mt*16 + lhi*4 + reg;
          po[(size_t)k*(H_OUTD*W_OUTD)] = acc[mt][nt][reg];
        }
      }
    }
  }
}

// ---------------- fallback (ws too small): naive fp32 ----------------
__global__ void naive_conv(const float* __restrict__ x, const float* __restrict__ ft,
                           float* __restrict__ out) {
  int idx = blockIdx.x*256 + threadIdx.x;
  int total = NBATCH*K_OUT*H_OUTD*W_OUTD;
  if (idx >= total) return;
  int w = idx % W_OUTD; int t = idx / W_OUTD;
  int h = t % H_OUTD; t /= H_OUTD;
  int k = t % K_OUT; int n = t / K_OUT;
  float acc = 0.f;
  for (int c = 0; c < C_IN; ++c)
    for (int r = 0; r < 3; ++r)
      for (int s = 0; s < 3; ++s)
        acc += x[((size_t)(n*C_IN + c)*H_IN + h + r)*W_IN + w + s]
             * ft[((k*C_IN + c)*3 + r)*3 + s];
  out[idx] = acc;
}

extern "C" void kernel_launch(void* const* d_in, const int* in_sizes, int n_in,
                              void* d_out, int out_size, void* d_ws, size_t ws_size,
                              hipStream_t stream) {
  (void)in_sizes; (void)n_in; (void)out_size;
  const float* x  = (const float*)d_in[0];
  const float* ft = (const float*)d_in[1];
  float* out = (float*)d_out;
  size_t need = (size_t)(XT_ELEMS + F_ELEMS) * sizeof(unsigned short);
  if (ws_size >= need) {
    unsigned short* xT = (unsigned short*)d_ws;
    unsigned short* F  = xT + XT_ELEMS;
    xpose_kernel<<<dim3(112, 32), 256, 0, stream>>>(x, xT);
    fprep_kernel<<<dim3(1152), 256, 0, stream>>>(ft, F);
    conv_gemm<<<dim3(97, 32), 512, 0, stream>>>(xT, F, out);
  } else {
    int total = NBATCH*K_OUT*H_OUTD*W_OUTD;
    naive_conv<<<(total + 255)/256, 256, 0, stream>>>(x, ft, out);
  }
}